// Round 1
// baseline (222.604 us; speedup 1.0000x reference)
//
#include <hip/hip_runtime.h>

typedef unsigned short ushort_t;
typedef __bf16 bf16x8 __attribute__((ext_vector_type(8)));
typedef float f32x4 __attribute__((ext_vector_type(4)));
typedef unsigned short ushortx8 __attribute__((ext_vector_type(8)));

#define NH 16
#define HS 64
#define CD 1024
#define NB 2
#define NT 2048
#define BT (NB * NT)   // 4096
#define N3 (3 * CD)    // 3072

// ---------- helpers ----------

__device__ __forceinline__ ushort_t bf16_rne(float f) {
  union { float f; unsigned u; } v; v.f = f;
  unsigned u = v.u;
  unsigned r = (u + 0x7FFFu + ((u >> 16) & 1u)) >> 16;
  return (ushort_t)r;
}

__device__ __forceinline__ void gload_lds16(const ushort_t* g, ushort_t* l) {
  __builtin_amdgcn_global_load_lds(
      (const __attribute__((address_space(1))) unsigned int*)g,
      (__attribute__((address_space(3))) unsigned int*)l, 16, 0, 0);
}

__device__ __forceinline__ f32x4 mfma16(ushortx8 a, ushortx8 b, f32x4 c) {
  return __builtin_amdgcn_mfma_f32_16x16x32_bf16(
      __builtin_bit_cast(bf16x8, a), __builtin_bit_cast(bf16x8, b), c, 0, 0, 0);
}

// ---------- pack kernels ----------

__global__ __launch_bounds__(256)
void pack_cast(const float4* __restrict__ in, ushort_t* __restrict__ out, int n4) {
  const int i = blockIdx.x * 256 + threadIdx.x;
  if (i >= n4) return;
  const float4 v = in[i];
  ushort4 r;
  r.x = bf16_rne(v.x); r.y = bf16_rne(v.y);
  r.z = bf16_rne(v.z); r.w = bf16_rne(v.w);
  *(ushort4*)(out + (size_t)i * 4) = r;
}

// Wq/Wk/Wv: [H][C][HS] fp32 -> Wqkv_t bf16 [3072 rows = s*1024+h*64+d][1024 cols = c]
__global__ __launch_bounds__(256)
void pack_wqkv(const float* __restrict__ Wq, const float* __restrict__ Wk,
               const float* __restrict__ Wv, ushort_t* __restrict__ out) {
  __shared__ ushort_t tile[64 * 66];
  const int sh = blockIdx.y;
  const int s = sh >> 4, h = sh & 15;
  const float* W = (s == 0) ? Wq : ((s == 1) ? Wk : Wv);
  const int c0 = blockIdx.x * 64;
  const int t = threadIdx.x;
#pragma unroll
  for (int j = 0; j < 16; ++j) {
    const int idx = t + j * 256;           // 0..4095
    const int ci = idx >> 6, d = idx & 63; // consecutive t -> consecutive d (coalesced read)
    const float v = W[(size_t)(h * 1024 + c0 + ci) * 64 + d];
    tile[d * 66 + ci] = bf16_rne(v);
  }
  __syncthreads();
#pragma unroll
  for (int j = 0; j < 16; ++j) {
    const int idx = t + j * 256;
    const int d = idx >> 6, ci = idx & 63; // consecutive t -> consecutive c (coalesced write)
    out[(size_t)(s * 1024 + h * 64 + d) * 1024 + c0 + ci] = tile[d * 66 + ci];
  }
}

// ---------- GEMM: C[m][n] = sum_k A[m][k] * Bt[n][k]  (both bf16 row-major in K) ----------
// 128x128 tile, BK=32, 4 waves (each 64x64), double-buffered LDS via global_load_lds.

template <bool OUT_BF16>
__global__ __launch_bounds__(256)
void gemm_bt(const ushort_t* __restrict__ A, const ushort_t* __restrict__ Bt,
             void* __restrict__ Cv, int M, int N, int K) {
  __shared__ __align__(16) ushort_t ldsA[2][128 * 32];
  __shared__ __align__(16) ushort_t ldsB[2][128 * 32];
  const int tid = threadIdx.x;
  const int lane = tid & 63;
  const int wave = tid >> 6;
  const int row0 = blockIdx.y * 128;
  const int col0 = blockIdx.x * 128;
  const int wm = wave >> 1, wn = wave & 1;

  f32x4 acc[4][4] = {};

  const int ce = (tid & 3) * 8;  // element col within 32-wide K tile

  auto stage = [&](int buf, int kt) {
    const int kbase = kt * 32;
#pragma unroll
    for (int j = 0; j < 2; ++j) {
      const int r = j * 64 + (tid >> 2);
      gload_lds16(A + (size_t)(row0 + r) * K + kbase + ce,
                  &ldsA[buf][(j * 256 + wave * 64) * 8]);
      gload_lds16(Bt + (size_t)(col0 + r) * K + kbase + ce,
                  &ldsB[buf][(j * 256 + wave * 64) * 8]);
    }
  };

  const int arow_off = (wm * 64 + (lane & 15)) * 32 + (lane >> 4) * 8;
  const int brow_off = (wn * 64 + (lane & 15)) * 32 + (lane >> 4) * 8;

  auto compute = [&](int buf) {
    ushortx8 af[4], bf[4];
#pragma unroll
    for (int m = 0; m < 4; ++m)
      af[m] = *(const ushortx8*)&ldsA[buf][arow_off + m * 512];
#pragma unroll
    for (int n = 0; n < 4; ++n)
      bf[n] = *(const ushortx8*)&ldsB[buf][brow_off + n * 512];
#pragma unroll
    for (int m = 0; m < 4; ++m)
#pragma unroll
      for (int n = 0; n < 4; ++n)
        acc[m][n] = mfma16(af[m], bf[n], acc[m][n]);
  };

  stage(0, 0);
  __syncthreads();
  const int nk = K >> 5;
  for (int kt = 0; kt < nk; ++kt) {
    const int cur = kt & 1;
    if (kt + 1 < nk) stage(cur ^ 1, kt + 1);
    compute(cur);
    __syncthreads();
  }

#pragma unroll
  for (int m = 0; m < 4; ++m) {
    const int rbase = row0 + wm * 64 + m * 16 + (lane >> 4) * 4;
#pragma unroll
    for (int n = 0; n < 4; ++n) {
      const int col = col0 + wn * 64 + n * 16 + (lane & 15);
#pragma unroll
      for (int i = 0; i < 4; ++i) {
        const size_t off = (size_t)(rbase + i) * N + col;
        if constexpr (OUT_BF16) ((ushort_t*)Cv)[off] = bf16_rne(acc[m][n][i]);
        else                    ((float*)Cv)[off]    = acc[m][n][i];
      }
    }
  }
}

// ---------- causal flash attention ----------
// QKV: [4096][3072] bf16 (cols: 0..1023=Q, 1024..2047=K, 2048..3071=V; col=h*64+d)
// O:   [4096][1024] bf16
// grid: x = T/64 q-tiles, y = B*H. 4 waves, wave w owns q rows q0+w*16..+15.

__global__ __launch_bounds__(256)
void attn_fwd(const ushort_t* __restrict__ QKV, ushort_t* __restrict__ O) {
  __shared__ __align__(16) ushort_t Klds[64 * 64];      // swizzled content, linear dest
  __shared__ __align__(16) ushort_t Vt[64 * 72];        // [d][key], pad 72 (16B-aligned rows)
  __shared__ __align__(16) ushort_t Plds[4][16 * 72];   // per-wave P, pad 72

  const int tid = threadIdx.x;
  const int lane = tid & 63;
  const int w = tid >> 6;
  const int bh = blockIdx.y;
  const int b = bh >> 4, h = bh & 15;
  const int q0 = blockIdx.x * 64;
  const size_t base_bt = (size_t)b * NT * N3;

  // Q fragments (held in registers for the whole kernel)
  const int qrow = q0 + w * 16 + (lane & 15);
  ushortx8 qf[2];
#pragma unroll
  for (int ks = 0; ks < 2; ++ks)
    qf[ks] = *(const ushortx8*)(QKV + base_bt + (size_t)qrow * N3 + h * 64 +
                                ks * 32 + (lane >> 4) * 8);

  float m_i[4], l_i[4];
  f32x4 acc[4] = {};
#pragma unroll
  for (int i = 0; i < 4; ++i) { m_i[i] = -INFINITY; l_i[i] = 0.f; }

  const int nkt = blockIdx.x;  // last (diagonal) key tile
  for (int kt = 0; kt <= nkt; ++kt) {
    __syncthreads();  // previous iteration's LDS reads done
    const int key0 = kt * 64;
    // --- stage K: global_load_lds, XOR-swizzle applied on the GLOBAL source ---
#pragma unroll
    for (int j = 0; j < 2; ++j) {
      const int o = j * 256 + tid;   // 16B chunk id 0..511
      const int row = o >> 3;        // key local
      const int slot = o & 7;
      const int src_chunk = slot ^ (row & 7);
      gload_lds16(QKV + base_bt + (size_t)(key0 + row) * N3 + 1024 + h * 64 + src_chunk * 8,
                  &Klds[(j * 256 + w * 64) * 8]);
    }
    // --- stage V transposed (reg staging; key=lane mapping keeps LDS writes ~2-way) ---
#pragma unroll
    for (int j2 = 0; j2 < 2; ++j2) {
      const int ch = j2 * 256 + tid;       // 0..511
      const int key = ch & 63;
      const int d0 = ((ch >> 6) & 7) * 8;
      const ushortx8 v = *(const ushortx8*)(QKV + base_bt + (size_t)(key0 + key) * N3 +
                                            2048 + h * 64 + d0);
#pragma unroll
      for (int e = 0; e < 8; ++e)
        Vt[(d0 + e) * 72 + key] = v[e];
    }
    __syncthreads();  // staging visible (drains vmcnt + lgkmcnt)

    // --- S = Q K^T ---
    f32x4 s[4] = {};
#pragma unroll
    for (int ks = 0; ks < 2; ++ks) {
#pragma unroll
      for (int n = 0; n < 4; ++n) {
        const int row = n * 16 + (lane & 15);
        const int c = ks * 4 + (lane >> 4);
        const ushortx8 kf = *(const ushortx8*)&Klds[row * 64 + ((c ^ (row & 7)) * 8)];
        s[n] = mfma16(qf[ks], kf, s[n]);
      }
    }

    // --- scale + causal mask (only diagonal tile) ---
    const bool diag = (kt == nkt);
    float p[4][4];
    float mx[4];
#pragma unroll
    for (int i = 0; i < 4; ++i) mx[i] = -INFINITY;
    const int myrow = w * 16 + (lane >> 4) * 4;  // local row base within 64-row block
#pragma unroll
    for (int n = 0; n < 4; ++n) {
      const int keyl = n * 16 + (lane & 15);
#pragma unroll
      for (int i = 0; i < 4; ++i) {
        float sv = s[n][i] * 0.03125f;  // scale = C^-0.5 = 1/32
        if (diag && (keyl > myrow + i)) sv = -INFINITY;
        p[n][i] = sv;
        mx[i] = fmaxf(mx[i], sv);
      }
    }
    // row max across the 16-lane group
#pragma unroll
    for (int i = 0; i < 4; ++i) {
      float v = mx[i];
#pragma unroll
      for (int off = 1; off < 16; off <<= 1)
        v = fmaxf(v, __shfl_xor(v, off, 64));
      mx[i] = v;
    }
    float alpha[4], rs[4];
#pragma unroll
    for (int i = 0; i < 4; ++i) {
      const float mn = fmaxf(m_i[i], mx[i]);
      alpha[i] = __expf(m_i[i] - mn);  // 0 on first tile (m=-inf)
      m_i[i] = mn;
      rs[i] = 0.f;
    }
#pragma unroll
    for (int n = 0; n < 4; ++n)
#pragma unroll
      for (int i = 0; i < 4; ++i) {
        const float e = __expf(p[n][i] - m_i[i]);  // masked -> exp(-inf)=0
        p[n][i] = e;
        rs[i] += e;
      }
#pragma unroll
    for (int i = 0; i < 4; ++i) {
      float v = rs[i];
#pragma unroll
      for (int off = 1; off < 16; off <<= 1)
        v += __shfl_xor(v, off, 64);
      l_i[i] = l_i[i] * alpha[i] + v;
    }
#pragma unroll
    for (int n = 0; n < 4; ++n)
#pragma unroll
      for (int i = 0; i < 4; ++i)
        acc[n][i] *= alpha[i];

    // --- P -> LDS (per-wave buffer) ---
#pragma unroll
    for (int n = 0; n < 4; ++n) {
      const int keyl = n * 16 + (lane & 15);
#pragma unroll
      for (int i = 0; i < 4; ++i)
        Plds[w][((lane >> 4) * 4 + i) * 72 + keyl] = bf16_rne(p[n][i]);
    }
    asm volatile("s_waitcnt lgkmcnt(0)" ::: "memory");

    // --- O += P V ---
#pragma unroll
    for (int ks = 0; ks < 2; ++ks) {
      const ushortx8 pa =
          *(const ushortx8*)&Plds[w][(lane & 15) * 72 + ks * 32 + (lane >> 4) * 8];
#pragma unroll
      for (int n = 0; n < 4; ++n) {
        const ushortx8 bv =
            *(const ushortx8*)&Vt[(n * 16 + (lane & 15)) * 72 + ks * 32 + (lane >> 4) * 8];
        acc[n] = mfma16(pa, bv, acc[n]);
      }
    }
  }

  // --- write O (bf16, [b*T+t][h*64+d]) ---
#pragma unroll
  for (int n = 0; n < 4; ++n) {
    const int col = h * 64 + n * 16 + (lane & 15);
#pragma unroll
    for (int i = 0; i < 4; ++i) {
      const int row = q0 + w * 16 + (lane >> 4) * 4 + i;
      O[((size_t)b * NT + row) * 1024 + col] = bf16_rne(acc[n][i] / l_i[i]);
    }
  }
}

// ---------- launch ----------

extern "C" void kernel_launch(void* const* d_in, const int* in_sizes, int n_in,
                              void* d_out, int out_size, void* d_ws, size_t ws_size,
                              hipStream_t stream) {
  (void)in_sizes; (void)n_in; (void)out_size; (void)ws_size;
  const float* x  = (const float*)d_in[0];
  const float* Wq = (const float*)d_in[1];
  const float* Wk = (const float*)d_in[2];
  const float* Wv = (const float*)d_in[3];
  const float* Wo = (const float*)d_in[4];

  char* ws = (char*)d_ws;
  ushort_t* Xbf    = (ushort_t*)(ws);                        // 4096x1024 bf16 (8 MB)
  ushort_t* Wqkv_t = (ushort_t*)(ws + 8388608);              // 3072x1024 bf16 (6 MB)
  ushort_t* Wo_bf  = (ushort_t*)(ws + 14680064);             // 1024x1024 bf16 (2 MB)
  ushort_t* QKV    = (ushort_t*)(ws + 16777216);             // 4096x3072 bf16 (24 MB)
  ushort_t* Obf    = (ushort_t*)(ws + 41943040);             // 4096x1024 bf16 (8 MB)

  pack_cast<<<4096, 256, 0, stream>>>((const float4*)x, Xbf, 1048576);
  pack_cast<<<1024, 256, 0, stream>>>((const float4*)Wo, Wo_bf, 262144);
  pack_wqkv<<<dim3(16, 48), 256, 0, stream>>>(Wq, Wk, Wv, Wqkv_t);

  gemm_bt<true><<<dim3(24, 32), 256, 0, stream>>>(Xbf, Wqkv_t, QKV, BT, N3, CD);
  attn_fwd<<<dim3(NT / 64, NB * NH), 256, 0, stream>>>(QKV, Obf);
  gemm_bt<false><<<dim3(8, 32), 256, 0, stream>>>(Obf, Wo_bf, d_out, BT, CD, CD);
}

// Round 2
// 147.921 us; speedup vs baseline: 1.5049x; 1.5049x over previous
//
#include <hip/hip_runtime.h>

typedef unsigned short ushort_t;
typedef __bf16 bf16x8 __attribute__((ext_vector_type(8)));
typedef float f32x4 __attribute__((ext_vector_type(4)));
typedef float f32x16 __attribute__((ext_vector_type(16)));
typedef unsigned short ushortx8 __attribute__((ext_vector_type(8)));
typedef unsigned int uintx4 __attribute__((ext_vector_type(4)));

#define NH 16
#define HS 64
#define CD 1024
#define NB 2
#define NT 2048
#define BT (NB * NT)   // 4096
#define N3 (3 * CD)    // 3072

#define L2E_DIV32 0.04508422002778011f  // log2(e) / 32  (scale = C^-0.5 = 1/32)

// ---------- helpers ----------

__device__ __forceinline__ ushort_t bf16_rne(float f) {
  union { float f; unsigned u; } v; v.f = f;
  unsigned u = v.u;
  unsigned r = (u + 0x7FFFu + ((u >> 16) & 1u)) >> 16;
  return (ushort_t)r;
}

__device__ __forceinline__ void gload_lds16(const ushort_t* g, ushort_t* l) {
  __builtin_amdgcn_global_load_lds(
      (const __attribute__((address_space(1))) unsigned int*)g,
      (__attribute__((address_space(3))) unsigned int*)l, 16, 0, 0);
}

__device__ __forceinline__ f32x4 mfma16(ushortx8 a, ushortx8 b, f32x4 c) {
  return __builtin_amdgcn_mfma_f32_16x16x32_bf16(
      __builtin_bit_cast(bf16x8, a), __builtin_bit_cast(bf16x8, b), c, 0, 0, 0);
}

__device__ __forceinline__ f32x16 mfma32(ushortx8 a, ushortx8 b, f32x16 c) {
  return __builtin_amdgcn_mfma_f32_32x32x16_bf16(
      __builtin_bit_cast(bf16x8, a), __builtin_bit_cast(bf16x8, b), c, 0, 0, 0);
}

__device__ __forceinline__ unsigned cvt_pk_bf16(float lo, float hi) {
  unsigned r;
  asm("v_cvt_pk_bf16_f32 %0, %1, %2" : "=v"(r) : "v"(lo), "v"(hi));
  return r;
}

// v_permlane32_swap_b32: a.hi <-> b.lo
__device__ __forceinline__ void plswap(unsigned &a, unsigned &b) {
  asm volatile("v_permlane32_swap_b32 %0, %1" : "+v"(a), "+v"(b));
}

// ---------- pack kernels ----------

__global__ __launch_bounds__(256)
void pack_cast(const float4* __restrict__ in, ushort_t* __restrict__ out, int n4) {
  const int i = blockIdx.x * 256 + threadIdx.x;
  if (i >= n4) return;
  const float4 v = in[i];
  ushort4 r;
  r.x = bf16_rne(v.x); r.y = bf16_rne(v.y);
  r.z = bf16_rne(v.z); r.w = bf16_rne(v.w);
  *(ushort4*)(out + (size_t)i * 4) = r;
}

// Wq/Wk/Wv: [H][C][HS] fp32 -> Wqkv_t bf16 [3072 rows = s*1024+h*64+d][1024 cols = c]
__global__ __launch_bounds__(256)
void pack_wqkv(const float* __restrict__ Wq, const float* __restrict__ Wk,
               const float* __restrict__ Wv, ushort_t* __restrict__ out) {
  __shared__ ushort_t tile[64 * 66];
  const int sh = blockIdx.y;
  const int s = sh >> 4, h = sh & 15;
  const float* W = (s == 0) ? Wq : ((s == 1) ? Wk : Wv);
  const int c0 = blockIdx.x * 64;
  const int t = threadIdx.x;
#pragma unroll
  for (int j = 0; j < 16; ++j) {
    const int idx = t + j * 256;           // 0..4095
    const int ci = idx >> 6, d = idx & 63; // consecutive t -> consecutive d (coalesced read)
    const float v = W[(size_t)(h * 1024 + c0 + ci) * 64 + d];
    tile[d * 66 + ci] = bf16_rne(v);
  }
  __syncthreads();
#pragma unroll
  for (int j = 0; j < 16; ++j) {
    const int idx = t + j * 256;
    const int d = idx >> 6, ci = idx & 63; // consecutive t -> consecutive c (coalesced write)
    out[(size_t)(s * 1024 + h * 64 + d) * 1024 + c0 + ci] = tile[d * 66 + ci];
  }
}

// ---------- GEMM: C[m][n] = sum_k A[m][k] * Bt[n][k]  (both bf16 row-major in K) ----------
// 128x128 tile, BK=32, 4 waves (each 64x64), double-buffered LDS via global_load_lds.

template <bool OUT_BF16>
__global__ __launch_bounds__(256)
void gemm_bt(const ushort_t* __restrict__ A, const ushort_t* __restrict__ Bt,
             void* __restrict__ Cv, int M, int N, int K) {
  __shared__ __align__(16) ushort_t ldsA[2][128 * 32];
  __shared__ __align__(16) ushort_t ldsB[2][128 * 32];
  const int tid = threadIdx.x;
  const int lane = tid & 63;
  const int wave = tid >> 6;
  const int row0 = blockIdx.y * 128;
  const int col0 = blockIdx.x * 128;
  const int wm = wave >> 1, wn = wave & 1;

  f32x4 acc[4][4] = {};

  const int ce = (tid & 3) * 8;  // element col within 32-wide K tile

  auto stage = [&](int buf, int kt) {
    const int kbase = kt * 32;
#pragma unroll
    for (int j = 0; j < 2; ++j) {
      const int r = j * 64 + (tid >> 2);
      gload_lds16(A + (size_t)(row0 + r) * K + kbase + ce,
                  &ldsA[buf][(j * 256 + wave * 64) * 8]);
      gload_lds16(Bt + (size_t)(col0 + r) * K + kbase + ce,
                  &ldsB[buf][(j * 256 + wave * 64) * 8]);
    }
  };

  const int arow_off = (wm * 64 + (lane & 15)) * 32 + (lane >> 4) * 8;
  const int brow_off = (wn * 64 + (lane & 15)) * 32 + (lane >> 4) * 8;

  auto compute = [&](int buf) {
    ushortx8 af[4], bf[4];
#pragma unroll
    for (int m = 0; m < 4; ++m)
      af[m] = *(const ushortx8*)&ldsA[buf][arow_off + m * 512];
#pragma unroll
    for (int n = 0; n < 4; ++n)
      bf[n] = *(const ushortx8*)&ldsB[buf][brow_off + n * 512];
#pragma unroll
    for (int m = 0; m < 4; ++m)
#pragma unroll
      for (int n = 0; n < 4; ++n)
        acc[m][n] = mfma16(af[m], bf[n], acc[m][n]);
  };

  stage(0, 0);
  __syncthreads();
  const int nk = K >> 5;
  for (int kt = 0; kt < nk; ++kt) {
    const int cur = kt & 1;
    if (kt + 1 < nk) stage(cur ^ 1, kt + 1);
    compute(cur);
    __syncthreads();
  }

#pragma unroll
  for (int m = 0; m < 4; ++m) {
    const int rbase = row0 + wm * 64 + m * 16 + (lane >> 4) * 4;
#pragma unroll
    for (int n = 0; n < 4; ++n) {
      const int col = col0 + wn * 64 + n * 16 + (lane & 15);
#pragma unroll
      for (int i = 0; i < 4; ++i) {
        const size_t off = (size_t)(rbase + i) * N + col;
        if constexpr (OUT_BF16) ((ushort_t*)Cv)[off] = bf16_rne(acc[m][n][i]);
        else                    ((float*)Cv)[off]    = acc[m][n][i];
      }
    }
  }
}

// ---------- causal flash attention v2 ----------
// QKV: [4096][3072] bf16 (cols: 0..1023=Q, 1024..2047=K, 2048..3071=V; col=h*64+d)
// O:   [4096][1024] bf16
// 4 waves x 32 q-rows = 128-row q-block. KVBLK=64. Double-buffered K/V in LDS,
// raw s_barrier + counted vmcnt, in-register softmax via swapped QK^T (mfma(K,Q)).

__global__ __launch_bounds__(256, 2)
void attn_fwd2(const ushort_t* __restrict__ QKV, ushort_t* __restrict__ O) {
  __shared__ __align__(16) ushort_t Klds[2][64 * 64];   // [key][d], 16B-chunk XOR-swizzled
  __shared__ __align__(16) ushort_t Vlds[2][64 * 64];   // [d][key], 16B-chunk XOR-swizzled

  const int tid = threadIdx.x;
  const int lane = tid & 63;
  const int w = tid >> 6;
  const int l31 = lane & 31;
  const int h = lane >> 5;

  // grid decode: XCD-grouped per bh, LPT (long q-blocks first)
  const int d0 = blockIdx.x;
  const int bh = (d0 & 7) + 8 * (d0 >> 7);
  const int qb = 15 - ((d0 >> 3) & 15);
  const int b = bh >> 4, head = bh & 15;
  const size_t base = (size_t)b * NT * N3;

  const int qw0 = qb * 128 + w * 32;
  const int qg = qw0 + l31;               // this lane's q row (within T)
  const int ntiles = 2 * qb + 2;
  const int tmax = 2 * qb + (w >> 1);     // last tile index this wave computes

  // ---- Q fragments in registers: qf[kc] = Q[qg][kc*16 + h*8 .. +7] ----
  ushortx8 qf[4];
  {
    const ushort_t* qp = QKV + base + (size_t)qg * N3 + head * 64 + h * 8;
#pragma unroll
    for (int kc = 0; kc < 4; ++kc)
      qf[kc] = *(const ushortx8*)(qp + kc * 16);
  }

  f32x16 oA = {}, oB = {};                // O^T acc: col=q(lane), row=d
  float m_r = -INFINITY, l_r = 0.f;

  const int vr = l31;                     // V stage: row-pair index
  const int vc = w * 2 + h;               // V stage: d-chunk 0..7

  // ---- prologue: stage tile 0 into buffer 0 ----
  ushortx8 vst0, vst1;
  {
    const ushort_t* vp = QKV + base + (size_t)(2 * vr) * N3 + 2048 + head * 64 + vc * 8;
    vst0 = *(const ushortx8*)(vp);
    vst1 = *(const ushortx8*)(vp + N3);
  }
#pragma unroll
  for (int i = 0; i < 2; ++i) {
    const int ch = i * 256 + tid;
    const int row = ch >> 3, cc = ch & 7;
    gload_lds16(QKV + base + (size_t)row * N3 + 1024 + head * 64 + ((cc ^ (row & 7)) * 8),
                &Klds[0][(i * 256 + w * 64) * 8]);
  }
#pragma unroll
  for (int e = 0; e < 8; ++e) {
    const int d = vc * 8 + e;
    ushort2 val; val.x = vst0[e]; val.y = vst1[e];
    *(ushort2*)((char*)&Vlds[0][0] + d * 128 + (((vr >> 2) ^ (d & 7)) * 16) + 4 * (vr & 3)) = val;
  }
  asm volatile("s_waitcnt lgkmcnt(0)" ::: "memory");

  int curb = 0;
  for (int t = 0; t < ntiles; ++t) {
    const bool hasn = (t + 1 < ntiles);
    const int nxt = curb ^ 1;
    if (hasn) {
      const int key0n = (t + 1) * 64;
      const ushort_t* vp =
          QKV + base + (size_t)(key0n + 2 * vr) * N3 + 2048 + head * 64 + vc * 8;
      vst0 = *(const ushortx8*)(vp);
      vst1 = *(const ushortx8*)(vp + N3);
#pragma unroll
      for (int i = 0; i < 2; ++i) {
        const int ch = i * 256 + tid;
        const int row = ch >> 3, cc = ch & 7;
        gload_lds16(QKV + base + (size_t)(key0n + row) * N3 + 1024 + head * 64 +
                        ((cc ^ (row & 7)) * 8),
                    &Klds[nxt][(i * 256 + w * 64) * 8]);
      }
      asm volatile("s_waitcnt vmcnt(4)" ::: "memory");  // prev tile's K landed; 4 newest fly
    } else {
      asm volatile("s_waitcnt vmcnt(0)" ::: "memory");
    }
    __builtin_amdgcn_s_barrier();
    asm volatile("" ::: "memory");

    if (t <= tmax) {
      const int key0 = t * 64;
      // --- S^T = K Q^T : col=q(lane), row=key ---
      f32x16 sA = {}, sB = {};
#pragma unroll
      for (int kc = 0; kc < 4; ++kc) {
        const int cc0 = ((2 * kc + h) ^ (l31 & 7)) * 8;
        const ushortx8 k0 = *(const ushortx8*)&Klds[curb][l31 * 64 + cc0];
        const ushortx8 k1 = *(const ushortx8*)&Klds[curb][(32 + l31) * 64 + cc0];
        sA = mfma32(k0, qf[kc], sA);
        sB = mfma32(k1, qf[kc], sB);
      }

      // --- scale into log2 domain (+ causal mask on diagonal tiles) ---
      float s[32];
#pragma unroll
      for (int r = 0; r < 16; ++r) {
        s[r]      = sA[r] * L2E_DIV32;
        s[16 + r] = sB[r] * L2E_DIV32;
      }
      if (key0 + 63 > qw0) {
        const int kb0 = key0 + 4 * h;
#pragma unroll
        for (int r = 0; r < 16; ++r) {
          const int krow = (r & 3) + 8 * (r >> 2);
          if (kb0 + krow > qg)      s[r]      = -INFINITY;
          if (kb0 + 32 + krow > qg) s[16 + r] = -INFINITY;
        }
      }

      // --- in-register online softmax (base-2) ---
      float mx = s[0];
#pragma unroll
      for (int r = 1; r < 32; ++r) mx = fmaxf(mx, s[r]);
      mx = fmaxf(mx, __shfl_xor(mx, 32, 64));
      const float mn = fmaxf(m_r, mx);
      const float alpha = exp2f(m_r - mn);
      m_r = mn;
      float rs = 0.f;
#pragma unroll
      for (int r = 0; r < 32; ++r) {
        s[r] = exp2f(s[r] - mn);
        rs += s[r];
      }
      rs += __shfl_xor(rs, 32, 64);
      l_r = l_r * alpha + rs;
#pragma unroll
      for (int r = 0; r < 16; ++r) { oA[r] *= alpha; oB[r] *= alpha; }

      // --- P -> bf16 pairs + permlane32 swaps -> P^T B-frags (T12) ---
      unsigned u[16];
#pragma unroll
      for (int j = 0; j < 16; ++j) u[j] = cvt_pk_bf16(s[2 * j], s[2 * j + 1]);
      plswap(u[0], u[2]);   plswap(u[1], u[3]);
      plswap(u[4], u[6]);   plswap(u[5], u[7]);
      plswap(u[8], u[10]);  plswap(u[9], u[11]);
      plswap(u[12], u[14]); plswap(u[13], u[15]);

      // --- O^T += V^T P^T ---
#pragma unroll
      for (int kc = 0; kc < 4; ++kc) {
        uintx4 pw;
        pw[0] = u[4 * kc + 0]; pw[1] = u[4 * kc + 1];
        pw[2] = u[4 * kc + 2]; pw[3] = u[4 * kc + 3];
        const ushortx8 pav = __builtin_bit_cast(ushortx8, pw);
        const int cc0 = ((2 * kc + h) ^ (l31 & 7)) * 8;
        const ushortx8 va = *(const ushortx8*)&Vlds[curb][l31 * 64 + cc0];
        const ushortx8 vb = *(const ushortx8*)&Vlds[curb][(32 + l31) * 64 + cc0];
        oA = mfma32(va, pav, oA);
        oB = mfma32(vb, pav, oB);
      }
    }

    if (hasn) {
#pragma unroll
      for (int e = 0; e < 8; ++e) {
        const int d = vc * 8 + e;
        ushort2 val; val.x = vst0[e]; val.y = vst1[e];
        *(ushort2*)((char*)&Vlds[nxt][0] + d * 128 + (((vr >> 2) ^ (d & 7)) * 16) +
                    4 * (vr & 3)) = val;
      }
    }
    asm volatile("s_waitcnt lgkmcnt(0)" ::: "memory");
    __builtin_amdgcn_s_barrier();
    asm volatile("" ::: "memory");
    curb ^= 1;
  }

  // --- epilogue: O[qg][head*64 + d] = acc / l ---
  const float inv_l = 1.0f / l_r;
  ushort_t* op = O + ((size_t)(b * NT + qg)) * 1024 + head * 64;
#pragma unroll
  for (int db = 0; db < 2; ++db) {
#pragma unroll
    for (int g = 0; g < 4; ++g) {
      ushort4 pk;
      if (db == 0) {
        pk.x = bf16_rne(oA[4 * g + 0] * inv_l);
        pk.y = bf16_rne(oA[4 * g + 1] * inv_l);
        pk.z = bf16_rne(oA[4 * g + 2] * inv_l);
        pk.w = bf16_rne(oA[4 * g + 3] * inv_l);
      } else {
        pk.x = bf16_rne(oB[4 * g + 0] * inv_l);
        pk.y = bf16_rne(oB[4 * g + 1] * inv_l);
        pk.z = bf16_rne(oB[4 * g + 2] * inv_l);
        pk.w = bf16_rne(oB[4 * g + 3] * inv_l);
      }
      *(ushort4*)(op + db * 32 + 8 * g + 4 * h) = pk;
    }
  }
}

// ---------- launch ----------

extern "C" void kernel_launch(void* const* d_in, const int* in_sizes, int n_in,
                              void* d_out, int out_size, void* d_ws, size_t ws_size,
                              hipStream_t stream) {
  (void)in_sizes; (void)n_in; (void)out_size; (void)ws_size;
  const float* x  = (const float*)d_in[0];
  const float* Wq = (const float*)d_in[1];
  const float* Wk = (const float*)d_in[2];
  const float* Wv = (const float*)d_in[3];
  const float* Wo = (const float*)d_in[4];

  char* ws = (char*)d_ws;
  ushort_t* Xbf    = (ushort_t*)(ws);                        // 4096x1024 bf16 (8 MB)
  ushort_t* Wqkv_t = (ushort_t*)(ws + 8388608);              // 3072x1024 bf16 (6 MB)
  ushort_t* Wo_bf  = (ushort_t*)(ws + 14680064);             // 1024x1024 bf16 (2 MB)
  ushort_t* QKV    = (ushort_t*)(ws + 16777216);             // 4096x3072 bf16 (24 MB)
  ushort_t* Obf    = (ushort_t*)(ws + 41943040);             // 4096x1024 bf16 (8 MB)

  pack_cast<<<4096, 256, 0, stream>>>((const float4*)x, Xbf, 1048576);
  pack_cast<<<1024, 256, 0, stream>>>((const float4*)Wo, Wo_bf, 262144);
  pack_wqkv<<<dim3(16, 48), 256, 0, stream>>>(Wq, Wk, Wv, Wqkv_t);

  gemm_bt<true><<<dim3(24, 32), 256, 0, stream>>>(Xbf, Wqkv_t, QKV, BT, N3, CD);
  attn_fwd2<<<dim3(512), 256, 0, stream>>>(QKV, Obf);
  gemm_bt<false><<<dim3(8, 32), 256, 0, stream>>>(Obf, Wo_bf, d_out, BT, CD, CD);
}